// Round 1
// baseline (416.198 us; speedup 1.0000x reference)
//
#include <hip/hip_runtime.h>
#include <hip/hip_bf16.h>
#include <cstdint>

// Problem constants
#define BB   16
#define PP   1024
#define EE   768
#define HID  768
#define NH   12
#define DH   64
#define NPB  (PP * EE)          // 786432 elements per batch
#define MROWS (BB * PP)         // 16384

typedef __bf16 bf16_t;
typedef __bf16 bf16x8 __attribute__((ext_vector_type(8)));
typedef float  f32x4  __attribute__((ext_vector_type(4)));

// ---------------------------------------------------------------------------
// Stage 1: per-slice partial sums for batch-global LayerNorm stats
// grid: 16*64 blocks, 256 threads. Each block: 12288 elems (3072 float4).
// ---------------------------------------------------------------------------
__global__ __launch_bounds__(256) void stats1_kernel(const float* __restrict__ x,
                                                     float* __restrict__ part) {
    int bid = blockIdx.x;
    int b = bid >> 6, s = bid & 63;
    const float4* xp = (const float4*)(x + (size_t)b * NPB + (size_t)s * 12288);
    float sum = 0.f, ss = 0.f;
#pragma unroll
    for (int i = 0; i < 12; ++i) {
        float4 v = xp[i * 256 + threadIdx.x];
        sum += v.x + v.y + v.z + v.w;
        ss  += v.x * v.x + v.y * v.y + v.z * v.z + v.w * v.w;
    }
    // wave reduce (64 lanes)
#pragma unroll
    for (int off = 32; off > 0; off >>= 1) {
        sum += __shfl_down(sum, off, 64);
        ss  += __shfl_down(ss,  off, 64);
    }
    __shared__ float tmp[8];
    int wave = threadIdx.x >> 6, lane = threadIdx.x & 63;
    if (lane == 0) { tmp[wave * 2] = sum; tmp[wave * 2 + 1] = ss; }
    __syncthreads();
    if (threadIdx.x == 0) {
        part[bid * 2]     = tmp[0] + tmp[2] + tmp[4] + tmp[6];
        part[bid * 2 + 1] = tmp[1] + tmp[3] + tmp[5] + tmp[7];
    }
}

// ---------------------------------------------------------------------------
// Stage 2: finalize mean / rstd per batch. grid: 16 blocks, 64 threads.
// ---------------------------------------------------------------------------
__global__ __launch_bounds__(64) void stats2_kernel(const float* __restrict__ part,
                                                    float* __restrict__ stats) {
    int b = blockIdx.x, l = threadIdx.x;
    float sum = part[(b * 64 + l) * 2];
    float ss  = part[(b * 64 + l) * 2 + 1];
#pragma unroll
    for (int off = 32; off > 0; off >>= 1) {
        sum += __shfl_down(sum, off, 64);
        ss  += __shfl_down(ss,  off, 64);
    }
    if (l == 0) {
        const float inv_n = 1.f / (float)NPB;
        float mean = sum * inv_n;
        float var  = ss * inv_n - mean * mean;
        stats[b * 2]     = mean;
        stats[b * 2 + 1] = rsqrtf(var + 1e-5f);
    }
}

// ---------------------------------------------------------------------------
// LN apply + cast to bf16. Each thread: 8 contiguous elements.
// grid: 12582912 / (256*8) = 6144 blocks.
// ---------------------------------------------------------------------------
__global__ __launch_bounds__(256) void ln_apply_kernel(const float* __restrict__ x,
                                                       const float* __restrict__ lnw,
                                                       const float* __restrict__ lnb,
                                                       const float* __restrict__ stats,
                                                       bf16_t* __restrict__ xn) {
    int i = (blockIdx.x * 256 + threadIdx.x) * 8;   // element index
    int b = i / NPB;
    int r = i - b * NPB;                             // index into (P,E) params
    float mean = stats[b * 2], rstd = stats[b * 2 + 1];
    float4 x0 = *(const float4*)(x + i),     x1 = *(const float4*)(x + i + 4);
    float4 w0 = *(const float4*)(lnw + r),   w1 = *(const float4*)(lnw + r + 4);
    float4 c0 = *(const float4*)(lnb + r),   c1 = *(const float4*)(lnb + r + 4);
    union { bf16_t h[8]; uint4 u; } o;
    o.h[0] = (bf16_t)((x0.x - mean) * rstd * w0.x + c0.x);
    o.h[1] = (bf16_t)((x0.y - mean) * rstd * w0.y + c0.y);
    o.h[2] = (bf16_t)((x0.z - mean) * rstd * w0.z + c0.z);
    o.h[3] = (bf16_t)((x0.w - mean) * rstd * w0.w + c0.w);
    o.h[4] = (bf16_t)((x1.x - mean) * rstd * w1.x + c1.x);
    o.h[5] = (bf16_t)((x1.y - mean) * rstd * w1.y + c1.y);
    o.h[6] = (bf16_t)((x1.z - mean) * rstd * w1.z + c1.z);
    o.h[7] = (bf16_t)((x1.w - mean) * rstd * w1.w + c1.w);
    *(uint4*)(xn + i) = o.u;
}

// ---------------------------------------------------------------------------
// Transpose + cast fp32 (R x C) -> bf16 (C x R).  dst[c*R + r] = src[r*C + c]
// ---------------------------------------------------------------------------
__global__ __launch_bounds__(256) void to_bf16_T_kernel(const float* __restrict__ src,
                                                        bf16_t* __restrict__ dst,
                                                        int R, int C) {
    int idx = blockIdx.x * 256 + threadIdx.x;
    if (idx >= R * C) return;
    int c = idx / R, r = idx - c * R;
    dst[idx] = (bf16_t)src[(size_t)r * C + c];
}

// ---------------------------------------------------------------------------
// Core 128x128 GEMM tile: C = A (MxK, row-major) * Bt^T (Bt is NxK row-major).
// 256 threads = 4 waves in 2x2; each wave computes 64x64 via 4x4 MFMA tiles.
// MFMA 16x16x32 bf16. A-frag: A[m=lane&15][k=quad*8+j]; B-frag: Bt[n][k].
// C/D: col = lane&15, row = quad*4 + reg.
// LDS row stride 40 elems (80 B): 2-way bank aliasing only (free).
// ---------------------------------------------------------------------------
template <int KDIM>
__device__ __forceinline__ void gemm_core_128(const bf16_t* __restrict__ A,
                                              const bf16_t* __restrict__ Bt,
                                              int mBase, int nBase,
                                              f32x4 acc[4][4]) {
    __shared__ bf16_t As[128][40];
    __shared__ bf16_t Bs[128][40];
    const int t = threadIdx.x;
    const int lane = t & 63, wave = t >> 6;
    const int wm = wave >> 1, wn = wave & 1;
    const int m16 = lane & 15, quad = lane >> 4;

    const f32x4 z = {0.f, 0.f, 0.f, 0.f};
#pragma unroll
    for (int mm = 0; mm < 4; ++mm)
#pragma unroll
        for (int nn = 0; nn < 4; ++nn) acc[mm][nn] = z;

    for (int k0 = 0; k0 < KDIM; k0 += 32) {
        __syncthreads();
#pragma unroll
        for (int r = 0; r < 2; ++r) {
            int f = r * 256 + t;
            int row = f >> 2, ch = (f & 3) * 8;
            *(bf16x8*)(&As[row][ch]) =
                *(const bf16x8*)(A + (size_t)(mBase + row) * KDIM + k0 + ch);
            *(bf16x8*)(&Bs[row][ch]) =
                *(const bf16x8*)(Bt + (size_t)(nBase + row) * KDIM + k0 + ch);
        }
        __syncthreads();
        bf16x8 af[4], bf[4];
#pragma unroll
        for (int i = 0; i < 4; ++i) {
            af[i] = *(const bf16x8*)(&As[wm * 64 + i * 16 + m16][quad * 8]);
            bf[i] = *(const bf16x8*)(&Bs[wn * 64 + i * 16 + m16][quad * 8]);
        }
#pragma unroll
        for (int mm = 0; mm < 4; ++mm)
#pragma unroll
            for (int nn = 0; nn < 4; ++nn)
                acc[mm][nn] = __builtin_amdgcn_mfma_f32_16x16x32_bf16(
                    af[mm], bf[nn], acc[mm][nn], 0, 0, 0);
    }
}

// ---------------------------------------------------------------------------
// GEMM1: proj = xn @ qkv, scattered into Q (B,H,P,DH), K (B,H,P,DH),
// Vt (B,H,DH,P), all bf16. grid (18, 128).
// ---------------------------------------------------------------------------
__global__ __launch_bounds__(256) void gemm_qkv_kernel(const bf16_t* __restrict__ xn,
                                                       const bf16_t* __restrict__ qkvT,
                                                       bf16_t* __restrict__ q,
                                                       bf16_t* __restrict__ kk,
                                                       bf16_t* __restrict__ vt) {
    f32x4 acc[4][4];
    const int mBase = blockIdx.y * 128, nBase = blockIdx.x * 128;
    gemm_core_128<768>(xn, qkvT, mBase, nBase, acc);

    const int lane = threadIdx.x & 63, wave = threadIdx.x >> 6;
    const int wm = wave >> 1, wn = wave & 1;
    const int m16 = lane & 15, quad = lane >> 4;
#pragma unroll
    for (int mm = 0; mm < 4; ++mm) {
#pragma unroll
        for (int i = 0; i < 4; ++i) {
            int row = mBase + wm * 64 + mm * 16 + quad * 4 + i;
            int b = row >> 10, p = row & 1023;
#pragma unroll
            for (int nn = 0; nn < 4; ++nn) {
                int col = nBase + wn * 64 + nn * 16 + m16;
                int h = col / 192, rem = col - h * 192;
                bf16_t bv = (bf16_t)acc[mm][nn][i];
                size_t bh = (size_t)(b * NH + h);
                if (rem < 64)       q[(bh * PP + p) * DH + rem]        = bv;
                else if (rem < 128) kk[(bh * PP + p) * DH + (rem-64)]  = bv;
                else                vt[(bh * DH + (rem-128)) * PP + p] = bv;
            }
        }
    }
}

// ---------------------------------------------------------------------------
// Fused attention (no softmax): O = (Q K^T) V per (b,h).
// grid (8 q-blocks, 192 bh). 256 threads, 4 waves.
// Phase S: 2x2 waves compute 128x128 S tile (K frags direct from global).
// S round-trips through LDS (bf16) to become the A operand of S@V.
// Phase O: 4 waves split 128 rows x 64 cols; V^T tile staged in LDS.
// ---------------------------------------------------------------------------
__global__ __launch_bounds__(256) void attn_kernel(const bf16_t* __restrict__ q,
                                                   const bf16_t* __restrict__ kk,
                                                   const bf16_t* __restrict__ vt,
                                                   bf16_t* __restrict__ o) {
    __shared__ bf16_t Ss[128][136];
    __shared__ bf16_t Vs[64][136];
    const int qb = blockIdx.x;
    const int bh = blockIdx.y;
    const int b = bh / NH, h = bh - b * NH;
    const bf16_t* Q = q  + (size_t)bh * PP * DH;
    const bf16_t* K = kk + (size_t)bh * PP * DH;
    const bf16_t* V = vt + (size_t)bh * DH * PP;

    const int t = threadIdx.x;
    const int lane = t & 63, wave = t >> 6;
    const int wm = wave >> 1, wn = wave & 1;
    const int m16 = lane & 15, quad = lane >> 4;
    const f32x4 z = {0.f, 0.f, 0.f, 0.f};

    // Q fragments for this wave's 64 rows, K = 64 (2 k-steps), kept in regs
    bf16x8 qf[4][2];
#pragma unroll
    for (int mm = 0; mm < 4; ++mm)
#pragma unroll
        for (int ks = 0; ks < 2; ++ks)
            qf[mm][ks] = *(const bf16x8*)(
                Q + (size_t)(qb * 128 + wm * 64 + mm * 16 + m16) * DH + ks * 32 + quad * 8);

    f32x4 oacc[2][4];
#pragma unroll
    for (int mm = 0; mm < 2; ++mm)
#pragma unroll
        for (int nn = 0; nn < 4; ++nn) oacc[mm][nn] = z;

    for (int jb = 0; jb < 8; ++jb) {
        // ---- S = Q K^T for this 128x128 tile (no LDS involved) ----
        f32x4 sacc[4][4];
#pragma unroll
        for (int mm = 0; mm < 4; ++mm)
#pragma unroll
            for (int nn = 0; nn < 4; ++nn) sacc[mm][nn] = z;
#pragma unroll
        for (int ks = 0; ks < 2; ++ks) {
            bf16x8 kf[4];
#pragma unroll
            for (int nn = 0; nn < 4; ++nn)
                kf[nn] = *(const bf16x8*)(
                    K + (size_t)(jb * 128 + wn * 64 + nn * 16 + m16) * DH + ks * 32 + quad * 8);
#pragma unroll
            for (int mm = 0; mm < 4; ++mm)
#pragma unroll
                for (int nn = 0; nn < 4; ++nn)
                    sacc[mm][nn] = __builtin_amdgcn_mfma_f32_16x16x32_bf16(
                        qf[mm][ks], kf[nn], sacc[mm][nn], 0, 0, 0);
        }
        __syncthreads();   // previous iteration's reads of Ss/Vs are done
        // ---- stage V^T tile (64 x 128) ----
#pragma unroll
        for (int r = 0; r < 4; ++r) {
            int f = r * 256 + t;
            int row = f >> 4, ch = (f & 15) * 8;
            *(bf16x8*)(&Vs[row][ch]) =
                *(const bf16x8*)(V + (size_t)row * PP + jb * 128 + ch);
        }
        // ---- write S tile to LDS as bf16 (C-layout -> A-layout transform) ----
#pragma unroll
        for (int mm = 0; mm < 4; ++mm)
#pragma unroll
            for (int nn = 0; nn < 4; ++nn)
#pragma unroll
                for (int i = 0; i < 4; ++i)
                    Ss[wm * 64 + mm * 16 + quad * 4 + i][wn * 64 + nn * 16 + m16] =
                        (bf16_t)sacc[mm][nn][i];
        __syncthreads();
        // ---- O += S_tile @ V_tile : each wave does 32 rows x 64 cols ----
#pragma unroll
        for (int ks = 0; ks < 4; ++ks) {
            bf16x8 afr[2], bfr[4];
#pragma unroll
            for (int mm = 0; mm < 2; ++mm)
                afr[mm] = *(const bf16x8*)(&Ss[wave * 32 + mm * 16 + m16][ks * 32 + quad * 8]);
#pragma unroll
            for (int nn = 0; nn < 4; ++nn)
                bfr[nn] = *(const bf16x8*)(&Vs[nn * 16 + m16][ks * 32 + quad * 8]);
#pragma unroll
            for (int mm = 0; mm < 2; ++mm)
#pragma unroll
                for (int nn = 0; nn < 4; ++nn)
                    oacc[mm][nn] = __builtin_amdgcn_mfma_f32_16x16x32_bf16(
                        afr[mm], bfr[nn], oacc[mm][nn], 0, 0, 0);
        }
    }
    // epilogue: O -> (B, P, HID) bf16
#pragma unroll
    for (int mm = 0; mm < 2; ++mm)
#pragma unroll
        for (int nn = 0; nn < 4; ++nn)
#pragma unroll
            for (int i = 0; i < 4; ++i) {
                int p = qb * 128 + wave * 32 + mm * 16 + quad * 4 + i;
                int d = nn * 16 + m16;
                o[((size_t)b * PP + p) * HID + h * DH + d] = (bf16_t)oacc[mm][nn][i];
            }
}

// ---------------------------------------------------------------------------
// GEMM3: out = relu(O @ lin_w + lin_b) + x  (fp32 out). grid (6, 128).
// ---------------------------------------------------------------------------
__global__ __launch_bounds__(256) void gemm_out_kernel(const bf16_t* __restrict__ o,
                                                       const bf16_t* __restrict__ lwT,
                                                       const float* __restrict__ linb,
                                                       const float* __restrict__ x,
                                                       float* __restrict__ out) {
    f32x4 acc[4][4];
    const int mBase = blockIdx.y * 128, nBase = blockIdx.x * 128;
    gemm_core_128<768>(o, lwT, mBase, nBase, acc);

    const int lane = threadIdx.x & 63, wave = threadIdx.x >> 6;
    const int wm = wave >> 1, wn = wave & 1;
    const int m16 = lane & 15, quad = lane >> 4;
#pragma unroll
    for (int mm = 0; mm < 4; ++mm) {
#pragma unroll
        for (int i = 0; i < 4; ++i) {
            size_t row = mBase + wm * 64 + mm * 16 + quad * 4 + i;
#pragma unroll
            for (int nn = 0; nn < 4; ++nn) {
                int col = nBase + wn * 64 + nn * 16 + m16;
                float v = acc[mm][nn][i] + linb[col];
                v = fmaxf(v, 0.f) + x[row * EE + col];
                out[row * EE + col] = v;
            }
        }
    }
}

// ---------------------------------------------------------------------------
// Launch
// ---------------------------------------------------------------------------
extern "C" void kernel_launch(void* const* d_in, const int* in_sizes, int n_in,
                              void* d_out, int out_size, void* d_ws, size_t ws_size,
                              hipStream_t stream) {
    const float* x    = (const float*)d_in[0];
    const float* lnw  = (const float*)d_in[1];
    const float* lnb  = (const float*)d_in[2];
    const float* qkvw = (const float*)d_in[3];
    const float* linw = (const float*)d_in[4];
    const float* linb = (const float*)d_in[5];
    float* out = (float*)d_out;
    char* ws = (char*)d_ws;

    // Workspace layout (bytes), 16B-aligned partitions, total ~105.4 MB
    float*  part  = (float*)(ws + 0);          //  8192 B
    float*  stats = (float*)(ws + 8192);       //   128 B
    bf16_t* xn    = (bf16_t*)(ws + 8448);      //  25165824 B
    bf16_t* qkvT  = (bf16_t*)(ws + 25174272);  //   3538944 B
    bf16_t* lwT   = (bf16_t*)(ws + 28713216);  //   1179648 B
    bf16_t* q     = (bf16_t*)(ws + 29892864);  //  25165824 B
    bf16_t* kk    = (bf16_t*)(ws + 55058688);  //  25165824 B
    bf16_t* vt    = (bf16_t*)(ws + 80224512);  //  25165824 B -> end 105390336
    bf16_t* o     = xn;  // xn dead after gemm_qkv; reuse for attention output

    stats1_kernel<<<dim3(BB * 64), dim3(256), 0, stream>>>(x, part);
    stats2_kernel<<<dim3(BB), dim3(64), 0, stream>>>(part, stats);
    ln_apply_kernel<<<dim3(6144), dim3(256), 0, stream>>>(x, lnw, lnb, stats, xn);
    to_bf16_T_kernel<<<dim3(6912), dim3(256), 0, stream>>>(qkvw, qkvT, 768, 2304);
    to_bf16_T_kernel<<<dim3(2304), dim3(256), 0, stream>>>(linw, lwT, 768, 768);
    gemm_qkv_kernel<<<dim3(18, 128), dim3(256), 0, stream>>>(xn, qkvT, q, kk, vt);
    attn_kernel<<<dim3(8, 192), dim3(256), 0, stream>>>(q, kk, vt, o);
    gemm_out_kernel<<<dim3(6, 128), dim3(256), 0, stream>>>(o, lwT, linb, x, out);
}

// Round 2
// 365.969 us; speedup vs baseline: 1.1372x; 1.1372x over previous
//
#include <hip/hip_runtime.h>
#include <hip/hip_bf16.h>
#include <cstdint>

// Problem constants
#define BB   16
#define PP   1024
#define EE   768
#define HID  768
#define NH   12
#define DH   64
#define NPB  (PP * EE)          // 786432 elements per batch
#define MROWS (BB * PP)         // 16384

typedef __bf16 bf16_t;
typedef __bf16 bf16x8 __attribute__((ext_vector_type(8)));
typedef float  f32x4  __attribute__((ext_vector_type(4)));

// Async global->LDS 16B DMA. LDS dest must be wave-uniform base + lane*16.
__device__ __forceinline__ void gld16(const void* g, void* l) {
    __builtin_amdgcn_global_load_lds(
        (const __attribute__((address_space(1))) void*)(uintptr_t)g,
        (__attribute__((address_space(3))) void*)(uint32_t)(uintptr_t)l,
        16, 0, 0);
}

// ---------------------------------------------------------------------------
// Stage 1: per-slice partial sums for batch-global LayerNorm stats
// ---------------------------------------------------------------------------
__global__ __launch_bounds__(256) void stats1_kernel(const float* __restrict__ x,
                                                     float* __restrict__ part) {
    int bid = blockIdx.x;
    int b = bid >> 6, s = bid & 63;
    const float4* xp = (const float4*)(x + (size_t)b * NPB + (size_t)s * 12288);
    float sum = 0.f, ss = 0.f;
#pragma unroll
    for (int i = 0; i < 12; ++i) {
        float4 v = xp[i * 256 + threadIdx.x];
        sum += v.x + v.y + v.z + v.w;
        ss  += v.x * v.x + v.y * v.y + v.z * v.z + v.w * v.w;
    }
#pragma unroll
    for (int off = 32; off > 0; off >>= 1) {
        sum += __shfl_down(sum, off, 64);
        ss  += __shfl_down(ss,  off, 64);
    }
    __shared__ float tmp[8];
    int wave = threadIdx.x >> 6, lane = threadIdx.x & 63;
    if (lane == 0) { tmp[wave * 2] = sum; tmp[wave * 2 + 1] = ss; }
    __syncthreads();
    if (threadIdx.x == 0) {
        part[bid * 2]     = tmp[0] + tmp[2] + tmp[4] + tmp[6];
        part[bid * 2 + 1] = tmp[1] + tmp[3] + tmp[5] + tmp[7];
    }
}

__global__ __launch_bounds__(64) void stats2_kernel(const float* __restrict__ part,
                                                    float* __restrict__ stats) {
    int b = blockIdx.x, l = threadIdx.x;
    float sum = part[(b * 64 + l) * 2];
    float ss  = part[(b * 64 + l) * 2 + 1];
#pragma unroll
    for (int off = 32; off > 0; off >>= 1) {
        sum += __shfl_down(sum, off, 64);
        ss  += __shfl_down(ss,  off, 64);
    }
    if (l == 0) {
        const float inv_n = 1.f / (float)NPB;
        float mean = sum * inv_n;
        float var  = ss * inv_n - mean * mean;
        stats[b * 2]     = mean;
        stats[b * 2 + 1] = rsqrtf(var + 1e-5f);
    }
}

__global__ __launch_bounds__(256) void ln_apply_kernel(const float* __restrict__ x,
                                                       const float* __restrict__ lnw,
                                                       const float* __restrict__ lnb,
                                                       const float* __restrict__ stats,
                                                       bf16_t* __restrict__ xn) {
    int i = (blockIdx.x * 256 + threadIdx.x) * 8;
    int b = i / NPB;
    int r = i - b * NPB;
    float mean = stats[b * 2], rstd = stats[b * 2 + 1];
    float4 x0 = *(const float4*)(x + i),     x1 = *(const float4*)(x + i + 4);
    float4 w0 = *(const float4*)(lnw + r),   w1 = *(const float4*)(lnw + r + 4);
    float4 c0 = *(const float4*)(lnb + r),   c1 = *(const float4*)(lnb + r + 4);
    union { bf16_t h[8]; uint4 u; } o;
    o.h[0] = (bf16_t)((x0.x - mean) * rstd * w0.x + c0.x);
    o.h[1] = (bf16_t)((x0.y - mean) * rstd * w0.y + c0.y);
    o.h[2] = (bf16_t)((x0.z - mean) * rstd * w0.z + c0.z);
    o.h[3] = (bf16_t)((x0.w - mean) * rstd * w0.w + c0.w);
    o.h[4] = (bf16_t)((x1.x - mean) * rstd * w1.x + c1.x);
    o.h[5] = (bf16_t)((x1.y - mean) * rstd * w1.y + c1.y);
    o.h[6] = (bf16_t)((x1.z - mean) * rstd * w1.z + c1.z);
    o.h[7] = (bf16_t)((x1.w - mean) * rstd * w1.w + c1.w);
    *(uint4*)(xn + i) = o.u;
}

__global__ __launch_bounds__(256) void to_bf16_T_kernel(const float* __restrict__ src,
                                                        bf16_t* __restrict__ dst,
                                                        int R, int C) {
    int idx = blockIdx.x * 256 + threadIdx.x;
    if (idx >= R * C) return;
    int c = idx / R, r = idx - c * R;
    dst[idx] = (bf16_t)src[(size_t)r * C + c];
}

// ---------------------------------------------------------------------------
// Core 128x128 GEMM tile via global_load_lds(16B) staging.
// LDS tiles 128x32 bf16, unpadded (DMA constraint); 16B chunk slots are
// swizzled per row-pair: LDS slot s at row r holds global chunk (s-(r>>1))&3,
// so frag reads land on 8 distinct bank-starts (2-way aliasing = free).
// ---------------------------------------------------------------------------
template <int KDIM>
__device__ __forceinline__ void gemm_core_128(const bf16_t* __restrict__ A,
                                              const bf16_t* __restrict__ Bt,
                                              int mBase, int nBase,
                                              f32x4 acc[4][4],
                                              bf16_t* As, bf16_t* Bs) {
    const int t = threadIdx.x;
    const int lane = t & 63, wave = t >> 6;
    const int wm = wave >> 1, wn = wave & 1;
    const int m16 = lane & 15, quad = lane >> 4;

    // staging coords (two 256-thread issues per 128x32 tile)
    const int r0 = t >> 2,       s0 = t & 3, g0 = (s0 - (r0 >> 1)) & 3;
    const int r1 = 64 + (t >> 2),            g1 = (s0 - (r1 >> 1)) & 3;
    const bf16_t* pa0 = A  + (size_t)(mBase + r0) * KDIM + g0 * 8;
    const bf16_t* pa1 = A  + (size_t)(mBase + r1) * KDIM + g1 * 8;
    const bf16_t* pb0 = Bt + (size_t)(nBase + r0) * KDIM + g0 * 8;
    const bf16_t* pb1 = Bt + (size_t)(nBase + r1) * KDIM + g1 * 8;
    bf16_t* la0 = As + t * 8;         bf16_t* la1 = As + (256 + t) * 8;
    bf16_t* lb0 = Bs + t * 8;         bf16_t* lb1 = Bs + (256 + t) * 8;

    const f32x4 z = {0.f, 0.f, 0.f, 0.f};
#pragma unroll
    for (int mm = 0; mm < 4; ++mm)
#pragma unroll
        for (int nn = 0; nn < 4; ++nn) acc[mm][nn] = z;

    int raOff[4], rbOff[4];
#pragma unroll
    for (int i = 0; i < 4; ++i) {
        int ra = wm * 64 + i * 16 + m16;
        raOff[i] = ra * 32 + (((quad + (ra >> 1)) & 3) * 8);
        int rb = wn * 64 + i * 16 + m16;
        rbOff[i] = rb * 32 + (((quad + (rb >> 1)) & 3) * 8);
    }

    for (int k0 = 0; k0 < KDIM; k0 += 32) {
        __syncthreads();
        gld16(pa0 + k0, la0);  gld16(pa1 + k0, la1);
        gld16(pb0 + k0, lb0);  gld16(pb1 + k0, lb1);
        __syncthreads();
        bf16x8 af[4], bfv[4];
#pragma unroll
        for (int i = 0; i < 4; ++i) {
            af[i]  = *(const bf16x8*)(As + raOff[i]);
            bfv[i] = *(const bf16x8*)(Bs + rbOff[i]);
        }
#pragma unroll
        for (int mm = 0; mm < 4; ++mm)
#pragma unroll
            for (int nn = 0; nn < 4; ++nn)
                acc[mm][nn] = __builtin_amdgcn_mfma_f32_16x16x32_bf16(
                    af[mm], bfv[nn], acc[mm][nn], 0, 0, 0);
    }
}

// ---------------------------------------------------------------------------
// GEMM1: proj = xn @ qkv. Epilogue goes through LDS so all global stores are
// 16B full-line writes. q,k,v all land in (B,H,P,DH) layout (v transposed by
// a separate kernel). grid (18, 128).
// ---------------------------------------------------------------------------
__global__ __launch_bounds__(256) void gemm_qkv_kernel(const bf16_t* __restrict__ xn,
                                                       const bf16_t* __restrict__ qkvT,
                                                       bf16_t* __restrict__ q,
                                                       bf16_t* __restrict__ kk,
                                                       bf16_t* __restrict__ v) {
    __shared__ bf16_t smem[8704];   // As(4096) + Bs(4096) for K-loop; T 64x136 epilogue
    f32x4 acc[4][4];
    const int mBase = blockIdx.y * 128, nBase = blockIdx.x * 128;
    gemm_core_128<768>(xn, qkvT, mBase, nBase, acc, smem, smem + 4096);

    const int t = threadIdx.x;
    const int lane = t & 63, wave = t >> 6;
    const int wm = wave >> 1, wn = wave & 1;
    const int m16 = lane & 15, quad = lane >> 4;

#pragma unroll
    for (int h2 = 0; h2 < 2; ++h2) {
        __syncthreads();
        if (wm == h2) {
#pragma unroll
            for (int mm = 0; mm < 4; ++mm)
#pragma unroll
                for (int nn = 0; nn < 4; ++nn)
#pragma unroll
                    for (int i = 0; i < 4; ++i) {
                        int r = mm * 16 + quad * 4 + i;
                        int c = wn * 64 + nn * 16 + m16;
                        smem[r * 136 + c] = (bf16_t)acc[mm][nn][i];
                    }
        }
        __syncthreads();
#pragma unroll
        for (int it = 0; it < 4; ++it) {
            int slot = it * 256 + t;
            int r = slot >> 4, cc = slot & 15;
            int row = mBase + h2 * 64 + r;
            int b = row >> 10, p = row & 1023;
            int col = nBase + cc * 8;
            int h = col / 192, rem = col - h * 192;
            size_t bh = (size_t)(b * NH + h);
            bf16x8 val = *(const bf16x8*)(smem + r * 136 + cc * 8);
            bf16_t* dst;
            if (rem < 64)       dst = q  + (bh * PP + p) * DH + rem;
            else if (rem < 128) dst = kk + (bh * PP + p) * DH + (rem - 64);
            else                dst = v  + (bh * PP + p) * DH + (rem - 128);
            *(bf16x8*)dst = val;
        }
    }
}

// ---------------------------------------------------------------------------
// v (B,H,P,DH) -> vt (B,H,DH,P). 64x64 tiles through LDS; chunk-swizzled so
// both sides are conflict-free; global access coalesced both sides.
// grid (16, 192).
// ---------------------------------------------------------------------------
__global__ __launch_bounds__(256) void vtrans_kernel(const bf16_t* __restrict__ v,
                                                     bf16_t* __restrict__ vt) {
    __shared__ bf16_t Ls[64 * 64];
    const int bh = blockIdx.y;
    const int p0 = blockIdx.x * 64;
    const bf16_t* src = v + ((size_t)bh * PP + p0) * DH;
    bf16_t* dstb = vt + (size_t)bh * DH * PP + p0;
    const int t = threadIdx.x;
#pragma unroll
    for (int it = 0; it < 2; ++it) {
        int f = it * 256 + t;
        int row = f >> 3, s = f & 7;
        int dg = (s - (row >> 3)) & 7;          // slot s holds global d-chunk dg
        *(bf16x8*)(&Ls[row * 64 + s * 8]) = *(const bf16x8*)(src + row * DH + dg * 8);
    }
    __syncthreads();
#pragma unroll
    for (int it = 0; it < 2; ++it) {
        int sl = it * 256 + t;
        int pc = sl & 7, d = sl >> 3;
        int slot = ((d >> 3) + pc) & 7;
        union { bf16_t h[8]; uint4 u4; } pk;
#pragma unroll
        for (int j = 0; j < 8; ++j)
            pk.h[j] = Ls[(pc * 8 + j) * 64 + slot * 8 + (d & 7)];
        *(uint4*)(dstb + (size_t)d * PP + pc * 8) = pk.u4;
    }
}

// ---------------------------------------------------------------------------
// Fused attention (no softmax): O = (Q K^T) V per (b,h). grid (8, 192).
// V tile staged via global_load_lds with 16-chunk swizzle (slot = (c+d)&15).
// ---------------------------------------------------------------------------
__global__ __launch_bounds__(256) void attn_kernel(const bf16_t* __restrict__ q,
                                                   const bf16_t* __restrict__ kk,
                                                   const bf16_t* __restrict__ vt,
                                                   bf16_t* __restrict__ o) {
    __shared__ bf16_t Ss[128 * 136];
    __shared__ bf16_t Vs[64 * 128];
    const int qb = blockIdx.x;
    const int bh = blockIdx.y;
    const int b = bh / NH, h = bh - b * NH;
    const bf16_t* Q = q  + (size_t)bh * PP * DH;
    const bf16_t* K = kk + (size_t)bh * PP * DH;
    const bf16_t* V = vt + (size_t)bh * DH * PP;

    const int t = threadIdx.x;
    const int lane = t & 63, wave = t >> 6;
    const int wm = wave >> 1, wn = wave & 1;
    const int m16 = lane & 15, quad = lane >> 4;
    const f32x4 z = {0.f, 0.f, 0.f, 0.f};

    bf16x8 qf[4][2];
#pragma unroll
    for (int mm = 0; mm < 4; ++mm)
#pragma unroll
        for (int ks = 0; ks < 2; ++ks)
            qf[mm][ks] = *(const bf16x8*)(
                Q + (size_t)(qb * 128 + wm * 64 + mm * 16 + m16) * DH + ks * 32 + quad * 8);

    f32x4 oacc[2][4];
#pragma unroll
    for (int mm = 0; mm < 2; ++mm)
#pragma unroll
        for (int nn = 0; nn < 4; ++nn) oacc[mm][nn] = z;

    for (int jb = 0; jb < 8; ++jb) {
        // ---- S = Q K^T (registers only) ----
        f32x4 sacc[4][4];
#pragma unroll
        for (int mm = 0; mm < 4; ++mm)
#pragma unroll
            for (int nn = 0; nn < 4; ++nn) sacc[mm][nn] = z;
#pragma unroll
        for (int ks = 0; ks < 2; ++ks) {
            bf16x8 kf[4];
#pragma unroll
            for (int nn = 0; nn < 4; ++nn)
                kf[nn] = *(const bf16x8*)(
                    K + (size_t)(jb * 128 + wn * 64 + nn * 16 + m16) * DH + ks * 32 + quad * 8);
#pragma unroll
            for (int mm = 0; mm < 4; ++mm)
#pragma unroll
                for (int nn = 0; nn < 4; ++nn)
                    sacc[mm][nn] = __builtin_amdgcn_mfma_f32_16x16x32_bf16(
                        qf[mm][ks], kf[nn], sacc[mm][nn], 0, 0, 0);
        }
        __syncthreads();   // previous iteration's Ss/Vs reads done
        // ---- DMA V^T tile (64 x 128), swizzled slots ----
#pragma unroll
        for (int r = 0; r < 4; ++r) {
            int f = r * 256 + t;
            int row = f >> 4, s = f & 15, g = (s - row) & 15;
            gld16(V + (size_t)row * PP + jb * 128 + g * 8, Vs + f * 8);
        }
        // ---- S tile to LDS bf16 (C-layout -> A-layout) ----
#pragma unroll
        for (int mm = 0; mm < 4; ++mm)
#pragma unroll
            for (int nn = 0; nn < 4; ++nn)
#pragma unroll
                for (int i = 0; i < 4; ++i)
                    Ss[(wm * 64 + mm * 16 + quad * 4 + i) * 136 + wn * 64 + nn * 16 + m16] =
                        (bf16_t)sacc[mm][nn][i];
        __syncthreads();
        // ---- O += S_tile @ V_tile ----
#pragma unroll
        for (int ks = 0; ks < 4; ++ks) {
            bf16x8 afr[2], bfr[4];
#pragma unroll
            for (int mm = 0; mm < 2; ++mm)
                afr[mm] = *(const bf16x8*)(
                    &Ss[(wave * 32 + mm * 16 + m16) * 136 + ks * 32 + quad * 8]);
#pragma unroll
            for (int nn = 0; nn < 4; ++nn) {
                int d = nn * 16 + m16;
                int slot = (ks * 4 + quad + d) & 15;
                bfr[nn] = *(const bf16x8*)(Vs + d * 128 + slot * 8);
            }
#pragma unroll
            for (int mm = 0; mm < 2; ++mm)
#pragma unroll
                for (int nn = 0; nn < 4; ++nn)
                    oacc[mm][nn] = __builtin_amdgcn_mfma_f32_16x16x32_bf16(
                        afr[mm], bfr[nn], oacc[mm][nn], 0, 0, 0);
        }
    }
#pragma unroll
    for (int mm = 0; mm < 2; ++mm)
#pragma unroll
        for (int nn = 0; nn < 4; ++nn)
#pragma unroll
            for (int i = 0; i < 4; ++i) {
                int p = qb * 128 + wave * 32 + mm * 16 + quad * 4 + i;
                int d = nn * 16 + m16;
                o[((size_t)b * PP + p) * HID + h * DH + d] = (bf16_t)oacc[mm][nn][i];
            }
}

// ---------------------------------------------------------------------------
// GEMM3: out = relu(O @ lin_w + lin_b) + x  (fp32 out). grid (6, 128).
// ---------------------------------------------------------------------------
__global__ __launch_bounds__(256) void gemm_out_kernel(const bf16_t* __restrict__ o,
                                                       const bf16_t* __restrict__ lwT,
                                                       const float* __restrict__ linb,
                                                       const float* __restrict__ x,
                                                       float* __restrict__ out) {
    __shared__ bf16_t smem[8192];
    f32x4 acc[4][4];
    const int mBase = blockIdx.y * 128, nBase = blockIdx.x * 128;
    gemm_core_128<768>(o, lwT, mBase, nBase, acc, smem, smem + 4096);

    const int lane = threadIdx.x & 63, wave = threadIdx.x >> 6;
    const int wm = wave >> 1, wn = wave & 1;
    const int m16 = lane & 15, quad = lane >> 4;
#pragma unroll
    for (int mm = 0; mm < 4; ++mm) {
#pragma unroll
        for (int i = 0; i < 4; ++i) {
            size_t row = mBase + wm * 64 + mm * 16 + quad * 4 + i;
#pragma unroll
            for (int nn = 0; nn < 4; ++nn) {
                int col = nBase + wn * 64 + nn * 16 + m16;
                float v = acc[mm][nn][i] + linb[col];
                v = fmaxf(v, 0.f) + x[row * EE + col];
                out[row * EE + col] = v;
            }
        }
    }
}

// ---------------------------------------------------------------------------
// Launch
// ---------------------------------------------------------------------------
extern "C" void kernel_launch(void* const* d_in, const int* in_sizes, int n_in,
                              void* d_out, int out_size, void* d_ws, size_t ws_size,
                              hipStream_t stream) {
    const float* x    = (const float*)d_in[0];
    const float* lnw  = (const float*)d_in[1];
    const float* lnb  = (const float*)d_in[2];
    const float* qkvw = (const float*)d_in[3];
    const float* linw = (const float*)d_in[4];
    const float* linb = (const float*)d_in[5];
    float* out = (float*)d_out;
    char* ws = (char*)d_ws;

    // Workspace layout (bytes), total ~105.4 MB. Buffer rotation:
    //   xn (A of gemm_qkv) -> dead -> reused as vt
    //   vslot: v (gemm_qkv out) -> dead after vtrans -> reused as o
    float*  part  = (float*)(ws + 0);          //  8192 B
    float*  stats = (float*)(ws + 8192);       //   128 B
    bf16_t* xn    = (bf16_t*)(ws + 8448);      //  25165824 B
    bf16_t* qkvT  = (bf16_t*)(ws + 25174272);  //   3538944 B
    bf16_t* lwT   = (bf16_t*)(ws + 28713216);  //   1179648 B
    bf16_t* q     = (bf16_t*)(ws + 29892864);  //  25165824 B
    bf16_t* kk    = (bf16_t*)(ws + 55058688);  //  25165824 B
    bf16_t* v     = (bf16_t*)(ws + 80224512);  //  25165824 B -> end 105390336
    bf16_t* vt    = xn;   // xn dead after gemm_qkv
    bf16_t* o     = v;    // v dead after vtrans

    stats1_kernel<<<dim3(BB * 64), dim3(256), 0, stream>>>(x, part);
    stats2_kernel<<<dim3(BB), dim3(64), 0, stream>>>(part, stats);
    ln_apply_kernel<<<dim3(6144), dim3(256), 0, stream>>>(x, lnw, lnb, stats, xn);
    to_bf16_T_kernel<<<dim3(6912), dim3(256), 0, stream>>>(qkvw, qkvT, 768, 2304);
    to_bf16_T_kernel<<<dim3(2304), dim3(256), 0, stream>>>(linw, lwT, 768, 768);
    gemm_qkv_kernel<<<dim3(18, 128), dim3(256), 0, stream>>>(xn, qkvT, q, kk, v);
    vtrans_kernel<<<dim3(16, 192), dim3(256), 0, stream>>>(v, vt);
    attn_kernel<<<dim3(8, 192), dim3(256), 0, stream>>>(q, kk, vt, o);
    gemm_out_kernel<<<dim3(6, 128), dim3(256), 0, stream>>>(o, lwT, linb, x, out);
}

// Round 3
// 293.297 us; speedup vs baseline: 1.4190x; 1.2478x over previous
//
#include <hip/hip_runtime.h>
#include <hip/hip_bf16.h>
#include <cstdint>

// Problem constants
#define BB   16
#define PP   1024
#define EE   768
#define HID  768
#define NH   12
#define DH   64
#define NPB  (PP * EE)          // 786432 elements per batch
#define MROWS (BB * PP)         // 16384

typedef __bf16 bf16_t;
typedef __bf16 bf16x8 __attribute__((ext_vector_type(8)));
typedef float  f32x4  __attribute__((ext_vector_type(4)));

// Async global->LDS 16B DMA. LDS dest must be wave-uniform base + lane*16.
__device__ __forceinline__ void gld16(const void* g, void* l) {
    __builtin_amdgcn_global_load_lds(
        (const __attribute__((address_space(1))) void*)(uintptr_t)g,
        (__attribute__((address_space(3))) void*)(uint32_t)(uintptr_t)l,
        16, 0, 0);
}

// ---------------------------------------------------------------------------
// Stage 1: per-slice partial sums for batch-global LayerNorm stats
// ---------------------------------------------------------------------------
__global__ __launch_bounds__(256) void stats1_kernel(const float* __restrict__ x,
                                                     float* __restrict__ part) {
    int bid = blockIdx.x;
    int b = bid >> 6, s = bid & 63;
    const float4* xp = (const float4*)(x + (size_t)b * NPB + (size_t)s * 12288);
    float sum = 0.f, ss = 0.f;
#pragma unroll
    for (int i = 0; i < 12; ++i) {
        float4 v = xp[i * 256 + threadIdx.x];
        sum += v.x + v.y + v.z + v.w;
        ss  += v.x * v.x + v.y * v.y + v.z * v.z + v.w * v.w;
    }
#pragma unroll
    for (int off = 32; off > 0; off >>= 1) {
        sum += __shfl_down(sum, off, 64);
        ss  += __shfl_down(ss,  off, 64);
    }
    __shared__ float tmp[8];
    int wave = threadIdx.x >> 6, lane = threadIdx.x & 63;
    if (lane == 0) { tmp[wave * 2] = sum; tmp[wave * 2 + 1] = ss; }
    __syncthreads();
    if (threadIdx.x == 0) {
        part[bid * 2]     = tmp[0] + tmp[2] + tmp[4] + tmp[6];
        part[bid * 2 + 1] = tmp[1] + tmp[3] + tmp[5] + tmp[7];
    }
}

__global__ __launch_bounds__(64) void stats2_kernel(const float* __restrict__ part,
                                                    float* __restrict__ stats) {
    int b = blockIdx.x, l = threadIdx.x;
    float sum = part[(b * 64 + l) * 2];
    float ss  = part[(b * 64 + l) * 2 + 1];
#pragma unroll
    for (int off = 32; off > 0; off >>= 1) {
        sum += __shfl_down(sum, off, 64);
        ss  += __shfl_down(ss,  off, 64);
    }
    if (l == 0) {
        const float inv_n = 1.f / (float)NPB;
        float mean = sum * inv_n;
        float var  = ss * inv_n - mean * mean;
        stats[b * 2]     = mean;
        stats[b * 2 + 1] = rsqrtf(var + 1e-5f);
    }
}

__global__ __launch_bounds__(256) void ln_apply_kernel(const float* __restrict__ x,
                                                       const float* __restrict__ lnw,
                                                       const float* __restrict__ lnb,
                                                       const float* __restrict__ stats,
                                                       bf16_t* __restrict__ xn) {
    int i = (blockIdx.x * 256 + threadIdx.x) * 8;
    int b = i / NPB;
    int r = i - b * NPB;
    float mean = stats[b * 2], rstd = stats[b * 2 + 1];
    float4 x0 = *(const float4*)(x + i),     x1 = *(const float4*)(x + i + 4);
    float4 w0 = *(const float4*)(lnw + r),   w1 = *(const float4*)(lnw + r + 4);
    float4 c0 = *(const float4*)(lnb + r),   c1 = *(const float4*)(lnb + r + 4);
    union { bf16_t h[8]; uint4 u; } o;
    o.h[0] = (bf16_t)((x0.x - mean) * rstd * w0.x + c0.x);
    o.h[1] = (bf16_t)((x0.y - mean) * rstd * w0.y + c0.y);
    o.h[2] = (bf16_t)((x0.z - mean) * rstd * w0.z + c0.z);
    o.h[3] = (bf16_t)((x0.w - mean) * rstd * w0.w + c0.w);
    o.h[4] = (bf16_t)((x1.x - mean) * rstd * w1.x + c1.x);
    o.h[5] = (bf16_t)((x1.y - mean) * rstd * w1.y + c1.y);
    o.h[6] = (bf16_t)((x1.z - mean) * rstd * w1.z + c1.z);
    o.h[7] = (bf16_t)((x1.w - mean) * rstd * w1.w + c1.w);
    *(uint4*)(xn + i) = o.u;
}

__global__ __launch_bounds__(256) void to_bf16_T_kernel(const float* __restrict__ src,
                                                        bf16_t* __restrict__ dst,
                                                        int R, int C) {
    int idx = blockIdx.x * 256 + threadIdx.x;
    if (idx >= R * C) return;
    int c = idx / R, r = idx - c * R;
    dst[idx] = (bf16_t)src[(size_t)r * C + c];
}

// ---------------------------------------------------------------------------
// Core 128x128 GEMM tile via global_load_lds(16B) staging.
// LDS tiles 128x32 bf16, unpadded (DMA constraint); 16B chunk slots are
// swizzled per row-pair so fragment reads sit at the free 2-way level.
// ---------------------------------------------------------------------------
template <int KDIM>
__device__ __forceinline__ void gemm_core_128(const bf16_t* __restrict__ A,
                                              const bf16_t* __restrict__ Bt,
                                              int mBase, int nBase,
                                              f32x4 acc[4][4],
                                              bf16_t* As, bf16_t* Bs) {
    const int t = threadIdx.x;
    const int lane = t & 63, wave = t >> 6;
    const int wm = wave >> 1, wn = wave & 1;
    const int m16 = lane & 15, quad = lane >> 4;

    const int r0 = t >> 2,       s0 = t & 3, g0 = (s0 - (r0 >> 1)) & 3;
    const int r1 = 64 + (t >> 2),            g1 = (s0 - (r1 >> 1)) & 3;
    const bf16_t* pa0 = A  + (size_t)(mBase + r0) * KDIM + g0 * 8;
    const bf16_t* pa1 = A  + (size_t)(mBase + r1) * KDIM + g1 * 8;
    const bf16_t* pb0 = Bt + (size_t)(nBase + r0) * KDIM + g0 * 8;
    const bf16_t* pb1 = Bt + (size_t)(nBase + r1) * KDIM + g1 * 8;
    bf16_t* la0 = As + t * 8;         bf16_t* la1 = As + (256 + t) * 8;
    bf16_t* lb0 = Bs + t * 8;         bf16_t* lb1 = Bs + (256 + t) * 8;

    const f32x4 z = {0.f, 0.f, 0.f, 0.f};
#pragma unroll
    for (int mm = 0; mm < 4; ++mm)
#pragma unroll
        for (int nn = 0; nn < 4; ++nn) acc[mm][nn] = z;

    int raOff[4], rbOff[4];
#pragma unroll
    for (int i = 0; i < 4; ++i) {
        int ra = wm * 64 + i * 16 + m16;
        raOff[i] = ra * 32 + (((quad + (ra >> 1)) & 3) * 8);
        int rb = wn * 64 + i * 16 + m16;
        rbOff[i] = rb * 32 + (((quad + (rb >> 1)) & 3) * 8);
    }

    for (int k0 = 0; k0 < KDIM; k0 += 32) {
        __syncthreads();
        gld16(pa0 + k0, la0);  gld16(pa1 + k0, la1);
        gld16(pb0 + k0, lb0);  gld16(pb1 + k0, lb1);
        __syncthreads();
        bf16x8 af[4], bfv[4];
#pragma unroll
        for (int i = 0; i < 4; ++i) {
            af[i]  = *(const bf16x8*)(As + raOff[i]);
            bfv[i] = *(const bf16x8*)(Bs + rbOff[i]);
        }
#pragma unroll
        for (int mm = 0; mm < 4; ++mm)
#pragma unroll
            for (int nn = 0; nn < 4; ++nn)
                acc[mm][nn] = __builtin_amdgcn_mfma_f32_16x16x32_bf16(
                    af[mm], bfv[nn], acc[mm][nn], 0, 0, 0);
    }
}

// ---------------------------------------------------------------------------
// GEMM1: proj = xn @ qkv. Epilogue: q written row-major (B,H,P,DH); k and v
// written TRANSPOSED (B,H,DH,P) via an in-LDS tile transpose. All global
// stores are 16B. Each 64-col half of the 128-col tile is wholly one class
// (gcd(192,64)=64). grid (18, 128).
// ---------------------------------------------------------------------------
__global__ __launch_bounds__(256) void gemm_qkv_kernel(const bf16_t* __restrict__ xn,
                                                       const bf16_t* __restrict__ qkvT,
                                                       bf16_t* __restrict__ q,
                                                       bf16_t* __restrict__ kt,
                                                       bf16_t* __restrict__ vt) {
    __shared__ bf16_t smem[9216];   // K-loop: As(4096)+Bs(4096). Epilogue: max 128x72
    f32x4 acc[4][4];
    const int mBase = blockIdx.y * 128, nBase = blockIdx.x * 128;
    gemm_core_128<768>(xn, qkvT, mBase, nBase, acc, smem, smem + 4096);

    const int t = threadIdx.x;
    const int lane = t & 63, wave = t >> 6;
    const int wm = wave >> 1, wn = wave & 1;
    const int m16 = lane & 15, quad = lane >> 4;
    const int b = mBase >> 10, p0 = mBase & 1023;

#pragma unroll
    for (int half = 0; half < 2; ++half) {
        const int g = blockIdx.x * 2 + half;
        const int cls = g % 3, h = g / 3;
        const size_t bh = (size_t)(b * NH + h);
        __syncthreads();   // prior phase LDS reads done
        if (cls == 0) {
            // ---- q: normal orientation, LDS stride 72 (16B-aligned rows) ----
            if (wn == half) {
#pragma unroll
                for (int mm = 0; mm < 4; ++mm)
#pragma unroll
                    for (int nn = 0; nn < 4; ++nn)
#pragma unroll
                        for (int i = 0; i < 4; ++i)
                            smem[(wm * 64 + mm * 16 + quad * 4 + i) * 72 + nn * 16 + m16] =
                                (bf16_t)acc[mm][nn][i];
            }
            __syncthreads();
#pragma unroll
            for (int it = 0; it < 4; ++it) {
                int slot = it * 256 + t;
                int r = slot >> 3, cc = slot & 7;
                bf16x8 val = *(const bf16x8*)(smem + r * 72 + cc * 8);
                *(bf16x8*)(q + (bh * PP + p0 + r) * DH + cc * 8) = val;
            }
        } else {
            // ---- k/v: transposed via LDS T[c][r], stride 136 ----
            bf16_t* dst = (cls == 1) ? kt : vt;
            if (wn == half) {
#pragma unroll
                for (int mm = 0; mm < 4; ++mm)
#pragma unroll
                    for (int nn = 0; nn < 4; ++nn) {
                        int c = nn * 16 + m16;
                        int r0 = wm * 64 + mm * 16 + quad * 4;
                        union { bf16_t hh[4]; uint2 u; } pk;
#pragma unroll
                        for (int i = 0; i < 4; ++i) pk.hh[i] = (bf16_t)acc[mm][nn][i];
                        *(uint2*)(&smem[c * 136 + r0]) = pk.u;
                    }
            }
            __syncthreads();
#pragma unroll
            for (int it = 0; it < 4; ++it) {
                int slot = it * 256 + t;
                int d = slot >> 4, pc = slot & 15;
                bf16x8 val = *(const bf16x8*)(smem + d * 136 + pc * 8);
                *(bf16x8*)(dst + (bh * DH + d) * PP + p0 + pc * 8) = val;
            }
        }
    }
}

// ---------------------------------------------------------------------------
// T = K^T V per head (associativity: (QK^T)V == Q(K^T V), no softmax).
// Computes Tt[d2][d1] = sum_p V[p][d2] K[p][d1] from vt/kt (B,H,DH,P).
// Split-K over 4 waves (256 p each), fp32 LDS reduce. T stored as bf16
// hi+lo pair (lossless to ~2^-17) to avoid new rounding error. grid (192).
// ---------------------------------------------------------------------------
__global__ __launch_bounds__(256) void kv_kernel(const bf16_t* __restrict__ kt,
                                                 const bf16_t* __restrict__ vt,
                                                 bf16_t* __restrict__ thi,
                                                 bf16_t* __restrict__ tlo) {
    __shared__ float red[4 * 64 * 65];   // 66.6 KB
    const int bh = blockIdx.x;
    const bf16_t* Vb = vt + (size_t)bh * DH * PP;
    const bf16_t* Kb = kt + (size_t)bh * DH * PP;
    const int t = threadIdx.x;
    const int lane = t & 63, wave = t >> 6;
    const int m16 = lane & 15, quad = lane >> 4;
    const f32x4 z = {0.f, 0.f, 0.f, 0.f};
    f32x4 acc[4][4];
#pragma unroll
    for (int mm = 0; mm < 4; ++mm)
#pragma unroll
        for (int nn = 0; nn < 4; ++nn) acc[mm][nn] = z;

    for (int ks = 0; ks < 8; ++ks) {
        int kb = wave * 256 + ks * 32 + quad * 8;
        bf16x8 af[4], bfv[4];
#pragma unroll
        for (int mm = 0; mm < 4; ++mm)
            af[mm] = *(const bf16x8*)(Vb + (size_t)(mm * 16 + m16) * PP + kb);
#pragma unroll
        for (int nn = 0; nn < 4; ++nn)
            bfv[nn] = *(const bf16x8*)(Kb + (size_t)(nn * 16 + m16) * PP + kb);
#pragma unroll
        for (int mm = 0; mm < 4; ++mm)
#pragma unroll
            for (int nn = 0; nn < 4; ++nn)
                acc[mm][nn] = __builtin_amdgcn_mfma_f32_16x16x32_bf16(
                    af[mm], bfv[nn], acc[mm][nn], 0, 0, 0);
    }
#pragma unroll
    for (int mm = 0; mm < 4; ++mm)
#pragma unroll
        for (int nn = 0; nn < 4; ++nn)
#pragma unroll
            for (int i = 0; i < 4; ++i)
                red[wave * 4160 + (mm * 16 + quad * 4 + i) * 65 + nn * 16 + m16] =
                    acc[mm][nn][i];
    __syncthreads();
#pragma unroll
    for (int j = 0; j < 16; ++j) {
        int idx = j * 256 + t;            // = m*64 + n
        int m = idx >> 6, n = idx & 63;
        int a = m * 65 + n;
        float s = red[a] + red[4160 + a] + red[8320 + a] + red[12480 + a];
        bf16_t hi = (bf16_t)s;
        float lo = s - (float)hi;
        thi[(size_t)bh * 4096 + idx] = hi;
        tlo[(size_t)bh * 4096 + idx] = (bf16_t)lo;
    }
}

// ---------------------------------------------------------------------------
// O = Q @ T per head. Kdim = 64 (d1), hi/lo double-MFMA on the T operand.
// Output o in (B, P, HID) bf16 row layout, 16B stores via LDS. grid (8, 192).
// ---------------------------------------------------------------------------
__global__ __launch_bounds__(256) void o_kernel(const bf16_t* __restrict__ q,
                                                const bf16_t* __restrict__ thi,
                                                const bf16_t* __restrict__ tlo,
                                                bf16_t* __restrict__ o) {
    __shared__ bf16_t N[128 * 72];
    const int bh = blockIdx.y;
    const int b = bh / NH, h = bh - b * NH;
    const int p0 = blockIdx.x * 128;
    const bf16_t* Qb = q + ((size_t)bh * PP + p0) * DH;
    const bf16_t* Th = thi + (size_t)bh * 4096;
    const bf16_t* Tl = tlo + (size_t)bh * 4096;
    const int t = threadIdx.x;
    const int lane = t & 63, wave = t >> 6;
    const int m16 = lane & 15, quad = lane >> 4;
    const f32x4 z = {0.f, 0.f, 0.f, 0.f};
    f32x4 acc[2][4];
#pragma unroll
    for (int mm = 0; mm < 2; ++mm)
#pragma unroll
        for (int nn = 0; nn < 4; ++nn) acc[mm][nn] = z;

#pragma unroll
    for (int ks = 0; ks < 2; ++ks) {
        bf16x8 af[2], bh_[4], bl_[4];
#pragma unroll
        for (int mm = 0; mm < 2; ++mm)
            af[mm] = *(const bf16x8*)(
                Qb + (size_t)(wave * 32 + mm * 16 + m16) * DH + ks * 32 + quad * 8);
#pragma unroll
        for (int nn = 0; nn < 4; ++nn) {
            bh_[nn] = *(const bf16x8*)(Th + (nn * 16 + m16) * 64 + ks * 32 + quad * 8);
            bl_[nn] = *(const bf16x8*)(Tl + (nn * 16 + m16) * 64 + ks * 32 + quad * 8);
        }
#pragma unroll
        for (int mm = 0; mm < 2; ++mm)
#pragma unroll
            for (int nn = 0; nn < 4; ++nn) {
                acc[mm][nn] = __builtin_amdgcn_mfma_f32_16x16x32_bf16(
                    af[mm], bh_[nn], acc[mm][nn], 0, 0, 0);
                acc[mm][nn] = __builtin_amdgcn_mfma_f32_16x16x32_bf16(
                    af[mm], bl_[nn], acc[mm][nn], 0, 0, 0);
            }
    }
#pragma unroll
    for (int mm = 0; mm < 2; ++mm)
#pragma unroll
        for (int nn = 0; nn < 4; ++nn)
#pragma unroll
            for (int i = 0; i < 4; ++i)
                N[(wave * 32 + mm * 16 + quad * 4 + i) * 72 + nn * 16 + m16] =
                    (bf16_t)acc[mm][nn][i];
    __syncthreads();
#pragma unroll
    for (int it = 0; it < 4; ++it) {
        int slot = it * 256 + t;
        int r = slot >> 3, cc = slot & 7;
        bf16x8 val = *(const bf16x8*)(N + r * 72 + cc * 8);
        *(bf16x8*)(o + ((size_t)(b * PP + p0 + r)) * HID + h * DH + cc * 8) = val;
    }
}

// ---------------------------------------------------------------------------
// GEMM3: out = relu(O @ lin_w + lin_b) + x  (fp32 out). grid (6, 128).
// ---------------------------------------------------------------------------
__global__ __launch_bounds__(256) void gemm_out_kernel(const bf16_t* __restrict__ o,
                                                       const bf16_t* __restrict__ lwT,
                                                       const float* __restrict__ linb,
                                                       const float* __restrict__ x,
                                                       float* __restrict__ out) {
    __shared__ bf16_t smem[8192];
    f32x4 acc[4][4];
    const int mBase = blockIdx.y * 128, nBase = blockIdx.x * 128;
    gemm_core_128<768>(o, lwT, mBase, nBase, acc, smem, smem + 4096);

    const int lane = threadIdx.x & 63, wave = threadIdx.x >> 6;
    const int wm = wave >> 1, wn = wave & 1;
    const int m16 = lane & 15, quad = lane >> 4;
#pragma unroll
    for (int mm = 0; mm < 4; ++mm) {
#pragma unroll
        for (int i = 0; i < 4; ++i) {
            size_t row = mBase + wm * 64 + mm * 16 + quad * 4 + i;
#pragma unroll
            for (int nn = 0; nn < 4; ++nn) {
                int col = nBase + wn * 64 + nn * 16 + m16;
                float v = acc[mm][nn][i] + linb[col];
                v = fmaxf(v, 0.f) + x[row * EE + col];
                out[row * EE + col] = v;
            }
        }
    }
}

// ---------------------------------------------------------------------------
// Launch
// ---------------------------------------------------------------------------
extern "C" void kernel_launch(void* const* d_in, const int* in_sizes, int n_in,
                              void* d_out, int out_size, void* d_ws, size_t ws_size,
                              hipStream_t stream) {
    const float* x    = (const float*)d_in[0];
    const float* lnw  = (const float*)d_in[1];
    const float* lnb  = (const float*)d_in[2];
    const float* qkvw = (const float*)d_in[3];
    const float* linw = (const float*)d_in[4];
    const float* linb = (const float*)d_in[5];
    float* out = (float*)d_out;
    char* ws = (char*)d_ws;

    // Workspace layout (bytes), total ~105.4 MB. Rotation:
    //   xn dead after gemm_qkv -> o ; qkvT dead after gemm_qkv -> Thi/Tlo
    float*  part  = (float*)(ws + 0);          //  8192 B
    float*  stats = (float*)(ws + 8192);       //   128 B
    bf16_t* xn    = (bf16_t*)(ws + 8448);      //  25165824 B
    bf16_t* qkvT  = (bf16_t*)(ws + 25174272);  //   3538944 B
    bf16_t* lwT   = (bf16_t*)(ws + 28713216);  //   1179648 B
    bf16_t* q     = (bf16_t*)(ws + 29892864);  //  25165824 B
    bf16_t* kt    = (bf16_t*)(ws + 55058688);  //  25165824 B
    bf16_t* vt    = (bf16_t*)(ws + 80224512);  //  25165824 B -> end 105390336
    bf16_t* thi   = qkvT;                      // 192*4096*2 = 1572864 B
    bf16_t* tlo   = qkvT + 192 * 4096;         // 1572864 B (fits 3.5 MB slot)
    bf16_t* o     = xn;                        // xn dead after gemm_qkv

    stats1_kernel<<<dim3(BB * 64), dim3(256), 0, stream>>>(x, part);
    stats2_kernel<<<dim3(BB), dim3(64), 0, stream>>>(part, stats);
    ln_apply_kernel<<<dim3(6144), dim3(256), 0, stream>>>(x, lnw, lnb, stats, xn);
    to_bf16_T_kernel<<<dim3(6912), dim3(256), 0, stream>>>(qkvw, qkvT, 768, 2304);
    to_bf16_T_kernel<<<dim3(2304), dim3(256), 0, stream>>>(linw, lwT, 768, 768);
    gemm_qkv_kernel<<<dim3(18, 128), dim3(256), 0, stream>>>(xn, qkvT, q, kt, vt);
    kv_kernel<<<dim3(192), dim3(256), 0, stream>>>(kt, vt, thi, tlo);
    o_kernel<<<dim3(8, 192), dim3(256), 0, stream>>>(q, thi, tlo, o);
    gemm_out_kernel<<<dim3(6, 128), dim3(256), 0, stream>>>(o, lwT, linb, x, out);
}

// Round 4
// 288.573 us; speedup vs baseline: 1.4423x; 1.0164x over previous
//
#include <hip/hip_runtime.h>
#include <hip/hip_bf16.h>
#include <cstdint>

// Problem constants
#define BB   16
#define PP   1024
#define EE   768
#define HID  768
#define NH   12
#define DH   64
#define NPB  (PP * EE)          // 786432 elements per batch
#define MROWS (BB * PP)         // 16384

typedef __bf16 bf16_t;
typedef __bf16 bf16x8 __attribute__((ext_vector_type(8)));
typedef float  f32x4  __attribute__((ext_vector_type(4)));

// Async global->LDS 16B DMA. LDS dest must be wave-uniform base + lane*16.
__device__ __forceinline__ void gld16(const void* g, void* l) {
    __builtin_amdgcn_global_load_lds(
        (const __attribute__((address_space(1))) void*)(uintptr_t)g,
        (__attribute__((address_space(3))) void*)(uint32_t)(uintptr_t)l,
        16, 0, 0);
}

// ---------------------------------------------------------------------------
// Stage 1: per-slice partial sums for batch-global LayerNorm stats
// ---------------------------------------------------------------------------
__global__ __launch_bounds__(256) void stats1_kernel(const float* __restrict__ x,
                                                     float* __restrict__ part) {
    int bid = blockIdx.x;
    int b = bid >> 6, s = bid & 63;
    const float4* xp = (const float4*)(x + (size_t)b * NPB + (size_t)s * 12288);
    float sum = 0.f, ss = 0.f;
#pragma unroll
    for (int i = 0; i < 12; ++i) {
        float4 v = xp[i * 256 + threadIdx.x];
        sum += v.x + v.y + v.z + v.w;
        ss  += v.x * v.x + v.y * v.y + v.z * v.z + v.w * v.w;
    }
#pragma unroll
    for (int off = 32; off > 0; off >>= 1) {
        sum += __shfl_down(sum, off, 64);
        ss  += __shfl_down(ss,  off, 64);
    }
    __shared__ float tmp[8];
    int wave = threadIdx.x >> 6, lane = threadIdx.x & 63;
    if (lane == 0) { tmp[wave * 2] = sum; tmp[wave * 2 + 1] = ss; }
    __syncthreads();
    if (threadIdx.x == 0) {
        part[bid * 2]     = tmp[0] + tmp[2] + tmp[4] + tmp[6];
        part[bid * 2 + 1] = tmp[1] + tmp[3] + tmp[5] + tmp[7];
    }
}

// ---------------------------------------------------------------------------
// prep: weight transposes to bf16 + stats finalize, one launch.
// blocks [0,6912): qkvT ; [6912,9216): lwT ; 9216: stats2.
// ---------------------------------------------------------------------------
__global__ __launch_bounds__(256) void prep_kernel(const float* __restrict__ qkvw,
                                                   const float* __restrict__ linw,
                                                   const float* __restrict__ part,
                                                   bf16_t* __restrict__ qkvT,
                                                   bf16_t* __restrict__ lwT,
                                                   float* __restrict__ stats) {
    int bid = blockIdx.x;
    if (bid < 6912) {
        int idx = bid * 256 + threadIdx.x;          // dst[c*768 + r]
        int c = idx / 768, r = idx - c * 768;
        qkvT[idx] = (bf16_t)qkvw[(size_t)r * 2304 + c];
    } else if (bid < 9216) {
        int idx = (bid - 6912) * 256 + threadIdx.x;
        int c = idx / 768, r = idx - c * 768;
        lwT[idx] = (bf16_t)linw[(size_t)r * 768 + c];
    } else {
        int wave = threadIdx.x >> 6, lane = threadIdx.x & 63;
#pragma unroll
        for (int j = 0; j < 4; ++j) {
            int b = wave * 4 + j;
            float sum = part[(b * 64 + lane) * 2];
            float ss  = part[(b * 64 + lane) * 2 + 1];
#pragma unroll
            for (int off = 32; off > 0; off >>= 1) {
                sum += __shfl_down(sum, off, 64);
                ss  += __shfl_down(ss,  off, 64);
            }
            if (lane == 0) {
                const float inv_n = 1.f / (float)NPB;
                float mean = sum * inv_n;
                float var  = ss * inv_n - mean * mean;
                stats[b * 2]     = mean;
                stats[b * 2 + 1] = rsqrtf(var + 1e-5f);
            }
        }
    }
}

__global__ __launch_bounds__(256) void ln_apply_kernel(const float* __restrict__ x,
                                                       const float* __restrict__ lnw,
                                                       const float* __restrict__ lnb,
                                                       const float* __restrict__ stats,
                                                       bf16_t* __restrict__ xn) {
    int i = (blockIdx.x * 256 + threadIdx.x) * 8;
    int b = i / NPB;
    int r = i - b * NPB;
    float mean = stats[b * 2], rstd = stats[b * 2 + 1];
    float4 x0 = *(const float4*)(x + i),     x1 = *(const float4*)(x + i + 4);
    float4 w0 = *(const float4*)(lnw + r),   w1 = *(const float4*)(lnw + r + 4);
    float4 c0 = *(const float4*)(lnb + r),   c1 = *(const float4*)(lnb + r + 4);
    union { bf16_t h[8]; uint4 u; } o;
    o.h[0] = (bf16_t)((x0.x - mean) * rstd * w0.x + c0.x);
    o.h[1] = (bf16_t)((x0.y - mean) * rstd * w0.y + c0.y);
    o.h[2] = (bf16_t)((x0.z - mean) * rstd * w0.z + c0.z);
    o.h[3] = (bf16_t)((x0.w - mean) * rstd * w0.w + c0.w);
    o.h[4] = (bf16_t)((x1.x - mean) * rstd * w1.x + c1.x);
    o.h[5] = (bf16_t)((x1.y - mean) * rstd * w1.y + c1.y);
    o.h[6] = (bf16_t)((x1.z - mean) * rstd * w1.z + c1.z);
    o.h[7] = (bf16_t)((x1.w - mean) * rstd * w1.w + c1.w);
    *(uint4*)(xn + i) = o.u;
}

// ---------------------------------------------------------------------------
// Core 128x128 GEMM tile, BK=64 (32 MFMA per barrier pair), DMA staging.
// LDS tiles 128x64 bf16 (8 chunks of 16B per row); physical chunk slot
// s = (logical + (row&7)) & 7 -> frag reads sit at the free 2-way level.
// LDS: As 16KB + Bs 16KB.
// ---------------------------------------------------------------------------
template <int KDIM>
__device__ __forceinline__ void gemm_core_128(const bf16_t* __restrict__ A,
                                              const bf16_t* __restrict__ Bt,
                                              int mBase, int nBase,
                                              f32x4 acc[4][4],
                                              bf16_t* As, bf16_t* Bs) {
    const int t = threadIdx.x;
    const int lane = t & 63, wave = t >> 6;
    const int wm = wave >> 1, wn = wave & 1;
    const int m16 = lane & 15, quad = lane >> 4;

    const int sr = t >> 3, s8 = t & 7;
    const bf16_t* pa[4]; const bf16_t* pb[4];
#pragma unroll
    for (int i = 0; i < 4; ++i) {
        int row = i * 32 + sr;
        int g = (s8 - (row & 7)) & 7;
        pa[i] = A  + (size_t)(mBase + row) * KDIM + g * 8;
        pb[i] = Bt + (size_t)(nBase + row) * KDIM + g * 8;
    }

    int raOff[4][2], rbOff[4][2];
#pragma unroll
    for (int i = 0; i < 4; ++i) {
        int ra = wm * 64 + i * 16 + m16;
        int rb = wn * 64 + i * 16 + m16;
#pragma unroll
        for (int ks = 0; ks < 2; ++ks) {
            raOff[i][ks] = ra * 64 + (((ks * 4 + quad) + (ra & 7)) & 7) * 8;
            rbOff[i][ks] = rb * 64 + (((ks * 4 + quad) + (rb & 7)) & 7) * 8;
        }
    }

    const f32x4 z = {0.f, 0.f, 0.f, 0.f};
#pragma unroll
    for (int mm = 0; mm < 4; ++mm)
#pragma unroll
        for (int nn = 0; nn < 4; ++nn) acc[mm][nn] = z;

    for (int k0 = 0; k0 < KDIM; k0 += 64) {
        __syncthreads();
#pragma unroll
        for (int i = 0; i < 4; ++i) {
            gld16(pa[i] + k0, As + i * 2048 + t * 8);
            gld16(pb[i] + k0, Bs + i * 2048 + t * 8);
        }
        __syncthreads();
#pragma unroll
        for (int ks = 0; ks < 2; ++ks) {
            bf16x8 af[4], bfv[4];
#pragma unroll
            for (int i = 0; i < 4; ++i) {
                af[i]  = *(const bf16x8*)(As + raOff[i][ks]);
                bfv[i] = *(const bf16x8*)(Bs + rbOff[i][ks]);
            }
#pragma unroll
            for (int mm = 0; mm < 4; ++mm)
#pragma unroll
                for (int nn = 0; nn < 4; ++nn)
                    acc[mm][nn] = __builtin_amdgcn_mfma_f32_16x16x32_bf16(
                        af[mm], bfv[nn], acc[mm][nn], 0, 0, 0);
        }
    }
}

// ---------------------------------------------------------------------------
// GEMM1: proj = xn @ qkv. q written row-major (B,P,HID); k,v transposed
// (B,H,DH,P) via in-LDS transpose. All global stores 16B. grid (18, 128).
// ---------------------------------------------------------------------------
__global__ __launch_bounds__(256) void gemm_qkv_kernel(const bf16_t* __restrict__ xn,
                                                       const bf16_t* __restrict__ qkvT,
                                                       bf16_t* __restrict__ q,
                                                       bf16_t* __restrict__ kt,
                                                       bf16_t* __restrict__ vt) {
    __shared__ bf16_t smem[16384];   // K-loop 32KB; epilogue reuse
    f32x4 acc[4][4];
    const int mBase = blockIdx.y * 128, nBase = blockIdx.x * 128;
    gemm_core_128<768>(xn, qkvT, mBase, nBase, acc, smem, smem + 8192);

    const int t = threadIdx.x;
    const int lane = t & 63, wave = t >> 6;
    const int wm = wave >> 1, wn = wave & 1;
    const int m16 = lane & 15, quad = lane >> 4;
    const int b = mBase >> 10, p0 = mBase & 1023;

#pragma unroll
    for (int half = 0; half < 2; ++half) {
        const int g = blockIdx.x * 2 + half;
        const int cls = g % 3, h = g / 3;
        const size_t bh = (size_t)(b * NH + h);
        __syncthreads();   // prior phase LDS reads done
        if (cls == 0) {
            // ---- q: row-major into (B,P,HID), LDS stride 72 ----
            if (wn == half) {
#pragma unroll
                for (int mm = 0; mm < 4; ++mm)
#pragma unroll
                    for (int nn = 0; nn < 4; ++nn)
#pragma unroll
                        for (int i = 0; i < 4; ++i)
                            smem[(wm * 64 + mm * 16 + quad * 4 + i) * 72 + nn * 16 + m16] =
                                (bf16_t)acc[mm][nn][i];
            }
            __syncthreads();
#pragma unroll
            for (int it = 0; it < 4; ++it) {
                int slot = it * 256 + t;
                int r = slot >> 3, cc = slot & 7;
                bf16x8 val = *(const bf16x8*)(smem + r * 72 + cc * 8);
                *(bf16x8*)(q + ((size_t)(b * PP + p0 + r)) * HID + h * DH + cc * 8) = val;
            }
        } else {
            // ---- k/v: transposed via LDS T[c][r], stride 136 ----
            bf16_t* dst = (cls == 1) ? kt : vt;
            if (wn == half) {
#pragma unroll
                for (int mm = 0; mm < 4; ++mm)
#pragma unroll
                    for (int nn = 0; nn < 4; ++nn) {
                        int c = nn * 16 + m16;
                        int r0 = wm * 64 + mm * 16 + quad * 4;
                        union { bf16_t hh[4]; uint2 u; } pk;
#pragma unroll
                        for (int i = 0; i < 4; ++i) pk.hh[i] = (bf16_t)acc[mm][nn][i];
                        *(uint2*)(&smem[c * 136 + r0]) = pk.u;
                    }
            }
            __syncthreads();
#pragma unroll
            for (int it = 0; it < 4; ++it) {
                int slot = it * 256 + t;
                int d = slot >> 4, pc = slot & 15;
                bf16x8 val = *(const bf16x8*)(smem + d * 136 + pc * 8);
                *(bf16x8*)(dst + (bh * DH + d) * PP + p0 + pc * 8) = val;
            }
        }
    }
}

// ---------------------------------------------------------------------------
// T_h = K^T V per head: T[d1][d2] = sum_p K[p][d1] V[p][d2], from kt/vt
// (B,H,DH,P). Split-K over 4 waves, fp32 LDS reduce, bf16 hi/lo out.
// grid (192).
// ---------------------------------------------------------------------------
__global__ __launch_bounds__(256) void kv_kernel(const bf16_t* __restrict__ kt,
                                                 const bf16_t* __restrict__ vt,
                                                 bf16_t* __restrict__ thi,
                                                 bf16_t* __restrict__ tlo) {
    __shared__ float red[4 * 64 * 65];   // 66.6 KB
    const int bh = blockIdx.x;
    const bf16_t* Kb = kt + (size_t)bh * DH * PP;
    const bf16_t* Vb = vt + (size_t)bh * DH * PP;
    const int t = threadIdx.x;
    const int lane = t & 63, wave = t >> 6;
    const int m16 = lane & 15, quad = lane >> 4;
    const f32x4 z = {0.f, 0.f, 0.f, 0.f};
    f32x4 acc[4][4];
#pragma unroll
    for (int mm = 0; mm < 4; ++mm)
#pragma unroll
        for (int nn = 0; nn < 4; ++nn) acc[mm][nn] = z;

    for (int ks = 0; ks < 8; ++ks) {
        int kb = wave * 256 + ks * 32 + quad * 8;
        bf16x8 af[4], bfv[4];
#pragma unroll
        for (int mm = 0; mm < 4; ++mm)
            af[mm] = *(const bf16x8*)(Kb + (size_t)(mm * 16 + m16) * PP + kb);
#pragma unroll
        for (int nn = 0; nn < 4; ++nn)
            bfv[nn] = *(const bf16x8*)(Vb + (size_t)(nn * 16 + m16) * PP + kb);
#pragma unroll
        for (int mm = 0; mm < 4; ++mm)
#pragma unroll
            for (int nn = 0; nn < 4; ++nn)
                acc[mm][nn] = __builtin_amdgcn_mfma_f32_16x16x32_bf16(
                    af[mm], bfv[nn], acc[mm][nn], 0, 0, 0);
    }
#pragma unroll
    for (int mm = 0; mm < 4; ++mm)
#pragma unroll
        for (int nn = 0; nn < 4; ++nn)
#pragma unroll
            for (int i = 0; i < 4; ++i)
                red[wave * 4160 + (mm * 16 + quad * 4 + i) * 65 + nn * 16 + m16] =
                    acc[mm][nn][i];
    __syncthreads();
#pragma unroll
    for (int j = 0; j < 16; ++j) {
        int idx = j * 256 + t;            // = d1*64 + d2
        int m = idx >> 6, n = idx & 63;
        int a = m * 65 + n;
        float s = red[a] + red[4160 + a] + red[8320 + a] + red[12480 + a];
        bf16_t hi = (bf16_t)s;
        float lo = s - (float)hi;
        thi[(size_t)bh * 4096 + idx] = hi;
        tlo[(size_t)bh * 4096 + idx] = (bf16_t)lo;
    }
}

// ---------------------------------------------------------------------------
// U^b[h*64+d1][e] = sum_d2 T_h[d1][d2] * lin_w[h*64+d2][e], stored TRANSPOSED
// as Ut[b][e][h*64+d1] (bf16) so it is the Bt operand of the final GEMM.
// T enters as hi/lo (no extra rounding). grid (192, 3), 256 thr.
// ---------------------------------------------------------------------------
__global__ __launch_bounds__(256) void u_kernel(const bf16_t* __restrict__ thi,
                                                const bf16_t* __restrict__ tlo,
                                                const bf16_t* __restrict__ lwT,
                                                bf16_t* __restrict__ ut) {
    const int bh = blockIdx.x;
    const int b = bh / NH, h = bh - b * NH;
    const int nBase = blockIdx.y * 256;
    const bf16_t* Th = thi + (size_t)bh * 4096;
    const bf16_t* Tl = tlo + (size_t)bh * 4096;
    const int t = threadIdx.x, lane = t & 63, wave = t >> 6;
    const int wm = wave >> 1, wn = wave & 1;
    const int m16 = lane & 15, quad = lane >> 4;
    const f32x4 z = {0.f, 0.f, 0.f, 0.f};
    f32x4 acc[2][8];
#pragma unroll
    for (int mm = 0; mm < 2; ++mm)
#pragma unroll
        for (int nn = 0; nn < 8; ++nn) acc[mm][nn] = z;

#pragma unroll
    for (int ks = 0; ks < 2; ++ks) {
        bf16x8 ah[2], al[2], bfr[8];
#pragma unroll
        for (int mm = 0; mm < 2; ++mm) {
            ah[mm] = *(const bf16x8*)(Th + (wm * 32 + mm * 16 + m16) * 64 + ks * 32 + quad * 8);
            al[mm] = *(const bf16x8*)(Tl + (wm * 32 + mm * 16 + m16) * 64 + ks * 32 + quad * 8);
        }
#pragma unroll
        for (int nn = 0; nn < 8; ++nn)
            bfr[nn] = *(const bf16x8*)(
                lwT + (size_t)(nBase + wn * 128 + nn * 16 + m16) * 768 + h * 64 + ks * 32 + quad * 8);
#pragma unroll
        for (int mm = 0; mm < 2; ++mm)
#pragma unroll
            for (int nn = 0; nn < 8; ++nn) {
                acc[mm][nn] = __builtin_amdgcn_mfma_f32_16x16x32_bf16(
                    ah[mm], bfr[nn], acc[mm][nn], 0, 0, 0);
                acc[mm][nn] = __builtin_amdgcn_mfma_f32_16x16x32_bf16(
                    al[mm], bfr[nn], acc[mm][nn], 0, 0, 0);
            }
    }
#pragma unroll
    for (int mm = 0; mm < 2; ++mm)
#pragma unroll
        for (int nn = 0; nn < 8; ++nn) {
            int e  = nBase + wn * 128 + nn * 16 + m16;
            int d1 = wm * 32 + mm * 16 + quad * 4;
            union { bf16_t hh[4]; uint2 u; } pk;
#pragma unroll
            for (int i = 0; i < 4; ++i) pk.hh[i] = (bf16_t)acc[mm][nn][i];
            *(uint2*)(ut + ((size_t)b * 768 + e) * 768 + h * 64 + d1) = pk.u;
        }
}

// ---------------------------------------------------------------------------
// Final GEMM: out = relu(q @ U^b + lin_b) + x  (fp32 out). grid (6, 128).
// ---------------------------------------------------------------------------
__global__ __launch_bounds__(256) void gemm_out_kernel(const bf16_t* __restrict__ q,
                                                       const bf16_t* __restrict__ ut,
                                                       const float* __restrict__ linb,
                                                       const float* __restrict__ x,
                                                       float* __restrict__ out) {
    __shared__ bf16_t smem[16384];
    f32x4 acc[4][4];
    const int mBase = blockIdx.y * 128, nBase = blockIdx.x * 128;
    const int b = mBase >> 10;
    gemm_core_128<768>(q, ut + (size_t)b * 768 * 768, mBase, nBase, acc,
                       smem, smem + 8192);

    const int lane = threadIdx.x & 63, wave = threadIdx.x >> 6;
    const int wm = wave >> 1, wn = wave & 1;
    const int m16 = lane & 15, quad = lane >> 4;
#pragma unroll
    for (int mm = 0; mm < 4; ++mm) {
#pragma unroll
        for (int i = 0; i < 4; ++i) {
            size_t row = mBase + wm * 64 + mm * 16 + quad * 4 + i;
#pragma unroll
            for (int nn = 0; nn < 4; ++nn) {
                int col = nBase + wn * 64 + nn * 16 + m16;
                float v = acc[mm][nn][i] + linb[col];
                v = fmaxf(v, 0.f) + x[row * EE + col];
                out[row * EE + col] = v;
            }
        }
    }
}

// ---------------------------------------------------------------------------
// Launch
// ---------------------------------------------------------------------------
extern "C" void kernel_launch(void* const* d_in, const int* in_sizes, int n_in,
                              void* d_out, int out_size, void* d_ws, size_t ws_size,
                              hipStream_t stream) {
    const float* x    = (const float*)d_in[0];
    const float* lnw  = (const float*)d_in[1];
    const float* lnb  = (const float*)d_in[2];
    const float* qkvw = (const float*)d_in[3];
    const float* linw = (const float*)d_in[4];
    const float* linb = (const float*)d_in[5];
    float* out = (float*)d_out;
    char* ws = (char*)d_ws;

    // Workspace layout (bytes), total ~105.4 MB. Rotation:
    //   qkvT dead after gemm_qkv -> thi/tlo ; kt dead after kv -> Ut
    float*  part  = (float*)(ws + 0);          //  8192 B
    float*  stats = (float*)(ws + 8192);       //   128 B
    bf16_t* xn    = (bf16_t*)(ws + 8448);      //  25165824 B
    bf16_t* qkvT  = (bf16_t*)(ws + 25174272);  //   3538944 B
    bf16_t* lwT   = (bf16_t*)(ws + 28713216);  //   1179648 B
    bf16_t* q     = (bf16_t*)(ws + 29892864);  //  25165824 B  (B,P,HID)
    bf16_t* kt    = (bf16_t*)(ws + 55058688);  //  25165824 B
    bf16_t* vt    = (bf16_t*)(ws + 80224512);  //  25165824 B -> end 105390336
    bf16_t* thi   = qkvT;                      // 1572864 B
    bf16_t* tlo   = qkvT + 192 * 4096;         // 1572864 B
    bf16_t* ut    = kt;                        // 18874368 B (kt dead after kv)

    stats1_kernel<<<dim3(BB * 64), dim3(256), 0, stream>>>(x, part);
    prep_kernel<<<dim3(9217), dim3(256), 0, stream>>>(qkvw, linw, part, qkvT, lwT, stats);
    ln_apply_kernel<<<dim3(6144), dim3(256), 0, stream>>>(x, lnw, lnb, stats, xn);
    gemm_qkv_kernel<<<dim3(18, 128), dim3(256), 0, stream>>>(xn, qkvT, q, kt, vt);
    kv_kernel<<<dim3(192), dim3(256), 0, stream>>>(kt, vt, thi, tlo);
    u_kernel<<<dim3(192, 3), dim3(256), 0, stream>>>(thi, tlo, lwT, ut);
    gemm_out_kernel<<<dim3(6, 128), dim3(256), 0, stream>>>(q, ut, linb, x, out);
}